// Round 9
// baseline (1072.589 us; speedup 1.0000x reference)
//
#include <hip/hip_runtime.h>
#include <hip/hip_bf16.h>
#include <stdint.h>

#define DEV __device__ __forceinline__

typedef __attribute__((ext_vector_type(8))) short bf16x8;
typedef __attribute__((ext_vector_type(8))) unsigned short u16x8;
typedef __attribute__((ext_vector_type(4))) unsigned short u16x4;
typedef __attribute__((ext_vector_type(4))) float f32x4;

static constexpr int BB = 4, NN = 8192, DD = 1024, HH = 8, DKK = 128, FFF = 4096;
static constexpr int MM = BB * NN;  // 32768

DEV float bfb2f(unsigned int s) { unsigned int x = s << 16; float f; __builtin_memcpy(&f, &x, 4); return f; }
DEV unsigned short f2bfb(float f) {
    unsigned int x; __builtin_memcpy(&x, &f, 4);
    x += 0x7fffu + ((x >> 16) & 1u);           // RNE
    return (unsigned short)(x >> 16);
}

DEV void gload_lds16(const void* g, void* l) {
    auto gp = (const __attribute__((address_space(1))) void*)(uintptr_t)g;
    auto lp = (__attribute__((address_space(3))) void*)(unsigned int)(uintptr_t)l;
    __builtin_amdgcn_global_load_lds(gp, lp, 16, 0, 0);
}

// ---------------- fp32 -> bf16 pack ----------------
__global__ void k_pack_bf16(const float* __restrict__ in, unsigned short* __restrict__ ob, long n) {
    long i = ((long)blockIdx.x * blockDim.x + threadIdx.x) * 8;
    if (i >= n) return;
    f32x4 a = *(const f32x4*)&in[i];
    f32x4 b = *(const f32x4*)&in[i + 4];
    u16x8 o;
    o[0]=f2bfb(a[0]); o[1]=f2bfb(a[1]); o[2]=f2bfb(a[2]); o[3]=f2bfb(a[3]);
    o[4]=f2bfb(b[0]); o[5]=f2bfb(b[1]); o[6]=f2bfb(b[2]); o[7]=f2bfb(b[3]);
    *(u16x8*)&ob[i] = o;
}

// ---------------- W [R,C] fp32 -> W^T [C,R] bf16 ----------------
DEV void transpose_body(const float* __restrict__ W, unsigned short* __restrict__ WT, int R, int C,
                        int bx, int by, int tid) {
    __shared__ float t[32][33];
    const int r0 = by * 32, c0 = bx * 32;
    const int lr = tid >> 3, lc = (tid & 7) * 4;
    f32x4 v = *(const f32x4*)&W[(long)(r0 + lr) * C + c0 + lc];
    t[lr][lc + 0] = v[0]; t[lr][lc + 1] = v[1]; t[lr][lc + 2] = v[2]; t[lr][lc + 3] = v[3];
    __syncthreads();
    const int oc = tid >> 3, orr = (tid & 7) * 4;
    u16x4 o;
    o[0] = f2bfb(t[orr + 0][oc]); o[1] = f2bfb(t[orr + 1][oc]);
    o[2] = f2bfb(t[orr + 2][oc]); o[3] = f2bfb(t[orr + 3][oc]);
    *(u16x4*)&WT[(long)(c0 + oc) * R + r0 + orr] = o;
}
__global__ void k_transpose(const float* __restrict__ W, unsigned short* __restrict__ WT, int R, int C) {
    transpose_body(W, WT, R, C, blockIdx.x, blockIdx.y, threadIdx.x);
}
__global__ void k_transpose_qkv(const float* __restrict__ Wq, const float* __restrict__ Wk,
                                const float* __restrict__ Wv, unsigned short* __restrict__ WT) {
    const float* W = blockIdx.z == 0 ? Wq : (blockIdx.z == 1 ? Wk : Wv);
    transpose_body(W, WT + (size_t)blockIdx.z * DD * DD, DD, DD, blockIdx.x, blockIdx.y, threadIdx.x);
}

// ============ 256x256 8-phase GEMM, persistent blocks + periodic ring ============
// Schedule identical to R8 (verified) except ds_reads spread 8/4/8/4 across phases.
// EPI 1: fused QKV: +bias; for K/V tiles fused per-head LN (+delta on K); head-layout bf16.
//        LN: per-row partials over wave's 4 cols -> fr-butterfly -> 8KB LDS combine
//        across the 2 waves sharing each head (256-col tile = 2 full heads).
// EPI 2: +bias, SiLU, bf16 ld=FFF
// EPI 3: +bias + resb(bf16), f32 out ld=DD
template <int EPI>
__global__ __launch_bounds__(512, 2)
void k_gemm256(const unsigned short* __restrict__ A, int lda,
               const unsigned short* __restrict__ BT, int ldbt,
               const float* __restrict__ bias0, const float* __restrict__ bias1,
               const float* __restrict__ bias2,
               const unsigned short* __restrict__ resb,
               unsigned short* __restrict__ outp0, unsigned short* __restrict__ outp1,
               unsigned short* __restrict__ outp2,
               float* __restrict__ outf,
               const float* __restrict__ gkp, const float* __restrict__ bekp,
               const float* __restrict__ dxp,
               int K, int gridx, int npass)
{
    extern __shared__ __align__(128) unsigned short smem[];
    unsigned short* As = smem;              // 4 slots * 8192 shorts
    unsigned short* Bs = smem + 4 * 8192;

    const int wg0 = (blockIdx.x & 7) * 32 + (blockIdx.x >> 3);   // XCD-chunked bijection

    const int tid = threadIdx.x;
    const int lane = tid & 63;
    const int w = tid >> 6;
    const int wm = w >> 2, wn = w & 3;      // 8 waves: 2M x 4N
    const int fr = lane & 15;
    const int kg = lane >> 4;

    const int dl = tid * 16;
    const int soff = dl ^ (((dl >> 7) & 3) << 4);
    const int arow = soff >> 6;
    const int akel = (soff & 63) >> 1;

    int aoff[8], boff[4];
    #pragma unroll
    for (int m = 0; m < 8; ++m) { int o = (wm * 128 + m * 16 + fr) * 64 + kg * 16; aoff[m] = o ^ (((o >> 7) & 3) << 4); }
    #pragma unroll
    for (int n = 0; n < 4; ++n) { int o = (wn * 64 + n * 16 + fr) * 64 + kg * 16; boff[n] = o ^ (((o >> 7) & 3) << 4); }

#define STG_A(base, u, ks, slot) do { \
        const unsigned short* _g = (base) + (long)(u) * 64 + (ks) * 32; \
        gload_lds16(_g,              (slot) + tid * 8); \
        gload_lds16(_g + 128L * lda, (slot) + 4096 + tid * 8); } while (0)
#define STG_B(base, u, ks, slot) do { \
        const unsigned short* _g = (base) + (long)(u) * 64 + (ks) * 32; \
        gload_lds16(_g,               (slot) + tid * 8); \
        gload_lds16(_g + 128L * ldbt, (slot) + 4096 + tid * 8); } while (0)

#define BAR() __builtin_amdgcn_s_barrier()
#define LGKM0() do { asm volatile("s_waitcnt lgkmcnt(0)" ::: "memory"); \
                     __builtin_amdgcn_sched_barrier(0); } while (0)
#define VM8() asm volatile("s_waitcnt vmcnt(8)" ::: "memory")

#define MFMA16(AF, BF, R0) do { \
        __builtin_amdgcn_s_setprio(1); \
        _Pragma("unroll") \
        for (int m = 0; m < 4; ++m) { \
            _Pragma("unroll") \
            for (int n = 0; n < 4; ++n) \
                acc[(R0) + m][n] = __builtin_amdgcn_mfma_f32_16x16x32_bf16(AF[m], BF[n], acc[(R0) + m][n], 0, 0, 0); \
        } \
        __builtin_amdgcn_s_setprio(0); } while (0)

    // reads spread 8/4/8/4; stage/wait placement identical to R8's verified ledger
#define DO_TILE(sa0, sa1, sb0, sb1, STG0, STG1, STG2, STG3) do { \
        bf16x8 b0f[4], a0f[4], a1f[4], b1f[4], a2f[4], a3f[4]; \
        /* ph0: 8 reads */ \
        _Pragma("unroll") \
        for (int n = 0; n < 4; ++n) b0f[n] = *(const bf16x8*)((const char*)(sb0) + boff[n]); \
        _Pragma("unroll") \
        for (int m = 0; m < 4; ++m) a0f[m] = *(const bf16x8*)((const char*)(sa0) + aoff[m]); \
        STG0; \
        BAR(); LGKM0(); \
        MFMA16(a0f, b0f, 0); \
        BAR(); \
        /* ph1: 4 reads */ \
        _Pragma("unroll") \
        for (int m = 0; m < 4; ++m) a1f[m] = *(const bf16x8*)((const char*)(sa0) + aoff[m + 4]); \
        STG1; VM8(); \
        BAR(); LGKM0(); \
        MFMA16(a1f, b0f, 4); \
        BAR(); \
        /* ph2: 8 reads */ \
        _Pragma("unroll") \
        for (int n = 0; n < 4; ++n) b1f[n] = *(const bf16x8*)((const char*)(sb1) + boff[n]); \
        _Pragma("unroll") \
        for (int m = 0; m < 4; ++m) a2f[m] = *(const bf16x8*)((const char*)(sa1) + aoff[m]); \
        STG2; \
        BAR(); LGKM0(); \
        MFMA16(a2f, b1f, 0); \
        BAR(); \
        /* ph3: 4 reads */ \
        _Pragma("unroll") \
        for (int m = 0; m < 4; ++m) a3f[m] = *(const bf16x8*)((const char*)(sa1) + aoff[m + 4]); \
        STG3; VM8(); \
        BAR(); LGKM0(); \
        MFMA16(a3f, b1f, 4); \
        BAR(); \
    } while (0)

    unsigned short* A0 = As;            unsigned short* A1 = As + 8192;
    unsigned short* A2 = As + 16384;    unsigned short* A3 = As + 24576;
    unsigned short* B0 = Bs;            unsigned short* B1 = Bs + 8192;
    unsigned short* B2 = Bs + 16384;    unsigned short* B3 = Bs + 24576;

    const int NT = K >> 6;

    int brow = ((wg0) / gridx) * 256;
    int bcol = ((wg0) % gridx) * 256;
    const unsigned short* Ab = A + (long)(brow + arow) * lda + akel;
    const unsigned short* Bb = BT + (long)(bcol + arow) * ldbt + akel;
    STG_A(Ab, 0, 0, A0); STG_B(Bb, 0, 0, B0);
    STG_B(Bb, 0, 1, B1); STG_A(Ab, 0, 1, A1);
    STG_A(Ab, 1, 0, A2); STG_B(Bb, 1, 0, B2);
    VM8();
    BAR();

    for (int p = 0; p < npass; ++p) {
        const int wgN = (p + 1 < npass) ? (wg0 + (p + 1) * 256) : wg0;
        const int browN = (wgN / gridx) * 256;
        const int bcolN = (wgN % gridx) * 256;
        const unsigned short* Ab2 = A + (long)(browN + arow) * lda + akel;
        const unsigned short* Bb2 = BT + (long)(bcolN + arow) * ldbt + akel;

        f32x4 acc[8][4] = {};

        for (int t = 0; t + 2 < NT; t += 2) {
            DO_TILE(A0, A1, B0, B1,
                    STG_B(Bb, t + 1, 1, B3), STG_A(Ab, t + 1, 1, A3),
                    STG_A(Ab, t + 2, 0, A0), STG_B(Bb, t + 2, 0, B0));
            DO_TILE(A2, A3, B2, B3,
                    STG_B(Bb, t + 2, 1, B1), STG_A(Ab, t + 2, 1, A1),
                    STG_A(Ab, t + 3, 0, A2), STG_B(Bb, t + 3, 0, B2));
        }
        DO_TILE(A0, A1, B0, B1,
                STG_B(Bb, NT - 1, 1, B3), STG_A(Ab, NT - 1, 1, A3),
                STG_A(Ab2, 0, 0, A0), STG_B(Bb2, 0, 0, B0));
        DO_TILE(A2, A3, B2, B3,
                STG_B(Bb2, 0, 1, B1), STG_A(Ab2, 0, 1, A1),
                STG_A(Ab2, 1, 0, A2), STG_B(Bb2, 1, 0, B2));

        // ---------------- epilogue ----------------
        const int q4 = (lane >> 4) * 4;
        if constexpr (EPI == 1) {
            const int mat = bcol >> 10;       // 0=Q, 1=K, 2=V
            const int dc0 = bcol & 1023;
            const float* bp = mat == 0 ? bias0 : (mat == 1 ? bias1 : bias2);
            unsigned short* op = mat == 0 ? outp0 : (mat == 1 ? outp1 : outp2);
            float bv[4];
            #pragma unroll
            for (int n = 0; n < 4; ++n) bv[n] = bp[dc0 + wn * 64 + n * 16 + fr];
            #pragma unroll
            for (int m = 0; m < 8; ++m)
                #pragma unroll
                for (int n = 0; n < 4; ++n)
                    #pragma unroll
                    for (int j = 0; j < 4; ++j) acc[m][n][j] += bv[n];

            if (mat == 0) {
                #pragma unroll
                for (int m = 0; m < 8; ++m)
                    #pragma unroll
                    for (int n = 0; n < 4; ++n) {
                        const int c = dc0 + wn * 64 + n * 16 + fr;
                        const int hh = c >> 7, dk = c & 127;
                        #pragma unroll
                        for (int j = 0; j < 4; ++j) {
                            const int r = brow + wm * 128 + m * 16 + q4 + j;
                            const long idx = (((long)(r >> 13) * 8 + hh) * 8192 + (r & 8191)) * 128 + dk;
                            op[idx] = f2bfb(acc[m][n][j]);
                        }
                    }
            } else {
                // fused per-head LN (+delta on K). red buffer after the 128KB ring.
                float2* red2 = (float2*)(smem + 65536);
                float ps[8][4], pq[8][4];
                #pragma unroll
                for (int m = 0; m < 8; ++m)
                    #pragma unroll
                    for (int j = 0; j < 4; ++j) {
                        float s = acc[m][0][j] + acc[m][1][j] + acc[m][2][j] + acc[m][3][j];
                        float qv = acc[m][0][j] * acc[m][0][j] + acc[m][1][j] * acc[m][1][j]
                                 + acc[m][2][j] * acc[m][2][j] + acc[m][3][j] * acc[m][3][j];
                        #pragma unroll
                        for (int o = 1; o < 16; o <<= 1) { s += __shfl_xor(s, o); qv += __shfl_xor(qv, o); }
                        ps[m][j] = s; pq[m][j] = qv;
                    }
                if (fr == 0) {
                    const int g4 = lane >> 4;
                    #pragma unroll
                    for (int m = 0; m < 8; ++m)
                        #pragma unroll
                        for (int j = 0; j < 4; ++j)
                            red2[wn * 256 + wm * 128 + m * 16 + g4 * 4 + j] = float2{ps[m][j], pq[m][j]};
                }
                BAR();
                float gkv[4], bkv[4];
                #pragma unroll
                for (int n = 0; n < 4; ++n) {
                    const int c = dc0 + wn * 64 + n * 16 + fr;
                    gkv[n] = gkp[c]; bkv[n] = bekp[c];
                }
                const int hbase = (wn >> 1) * 512;
                #pragma unroll
                for (int m = 0; m < 8; ++m)
                    #pragma unroll
                    for (int j = 0; j < 4; ++j) {
                        const int ri = wm * 128 + m * 16 + q4 + j;
                        const int r = brow + ri;
                        const float2 e0 = red2[hbase + ri];
                        const float2 e1 = red2[hbase + 256 + ri];
                        const float mean = (e0.x + e1.x) * (1.f / 128.f);
                        const float var  = (e0.y + e1.y) * (1.f / 128.f) - mean * mean;
                        const float rstd = rsqrtf(var + 1e-5f);
                        const float dmul = (mat == 1) ? dxp[r & 8191] : 1.f;
                        #pragma unroll
                        for (int n = 0; n < 4; ++n) {
                            const int c = dc0 + wn * 64 + n * 16 + fr;
                            const int hh = c >> 7, dk = c & 127;
                            float v = (acc[m][n][j] - mean) * rstd * gkv[n] + bkv[n];
                            v *= dmul;
                            const long idx = (((long)(r >> 13) * 8 + hh) * 8192 + (r & 8191)) * 128 + dk;
                            op[idx] = f2bfb(v);
                        }
                    }
                BAR();   // red2 reads done before next pass's epilogue rewrites it
            }
        } else if constexpr (EPI == 2) {
            #pragma unroll
            for (int m = 0; m < 8; ++m)
                #pragma unroll
                for (int n = 0; n < 4; ++n) {
                    const int c = bcol + wn * 64 + n * 16 + fr;
                    const float bv = bias0[c];
                    #pragma unroll
                    for (int j = 0; j < 4; ++j) {
                        const int r = brow + wm * 128 + m * 16 + q4 + j;
                        float v = acc[m][n][j] + bv;
                        v = v / (1.f + __expf(-v));
                        outp0[(long)r * FFF + c] = f2bfb(v);
                    }
                }
        } else {
            #pragma unroll
            for (int m = 0; m < 8; ++m)
                #pragma unroll
                for (int n = 0; n < 4; ++n) {
                    const int c = bcol + wn * 64 + n * 16 + fr;
                    const float bv = bias0[c];
                    #pragma unroll
                    for (int j = 0; j < 4; ++j) {
                        const int r = brow + wm * 128 + m * 16 + q4 + j;
                        float v = acc[m][n][j] + bv + bfb2f(resb[(long)r * DD + c]);
                        outf[(long)r * DD + c] = v;
                    }
                }
        }

        brow = browN; bcol = bcolN; Ab = Ab2; Bb = Bb2;
    }
    asm volatile("s_waitcnt vmcnt(0)" ::: "memory");
#undef DO_TILE
#undef MFMA16
#undef VM8
#undef LGKM0
#undef BAR
#undef STG_A
#undef STG_B
}

// ---------------- 128x128 GEMM (attn: EPI 3, residual from bf16 xb) ----------------
template <int EPI>
__global__ __launch_bounds__(256, 2)
void k_gemm(const unsigned short* __restrict__ A, int lda, long sAz,
            const unsigned short* __restrict__ BT, int ldbt, long sBz,
            const unsigned short* __restrict__ resb,
            unsigned short* __restrict__ outp,
            int K)
{
    __shared__ __align__(16) unsigned short As[128 * 32];
    __shared__ __align__(16) unsigned short Bs[128 * 32];
    const int tid = threadIdx.x;
    const int z = blockIdx.z;
    A  += (long)z * sAz;
    BT += (long)z * sBz;
    const int brow = blockIdx.y * 128;
    const int bcol = blockIdx.x * 128;

    const int c0 = tid, c1 = tid + 256;
    const unsigned short* Ap0 = A + (long)(brow + (c0 >> 2)) * lda + (c0 & 3) * 8;
    const unsigned short* Ap1 = A + (long)(brow + (c1 >> 2)) * lda + (c1 & 3) * 8;
    const unsigned short* Bp0 = BT + (long)(bcol + (c0 >> 2)) * ldbt + (c0 & 3) * 8;
    const unsigned short* Bp1 = BT + (long)(bcol + (c1 >> 2)) * ldbt + (c1 & 3) * 8;
    unsigned short* AsD0 = &As[c0 * 8];
    unsigned short* AsD1 = &As[c1 * 8];
    unsigned short* BsD0 = &Bs[c0 * 8];
    unsigned short* BsD1 = &Bs[c1 * 8];

    const int lane = tid & 63;
    const int w = tid >> 6;
    const int wr = (w >> 1) * 64;
    const int wc = (w & 1) * 64;
    const int fr = lane & 15;
    const int fk = (lane >> 4) * 8;

    f32x4 acc[4][4] = {};

    for (int kt = 0; kt < K; kt += 32) {
        gload_lds16(Ap0 + kt, AsD0);
        gload_lds16(Ap1 + kt, AsD1);
        gload_lds16(Bp0 + kt, BsD0);
        gload_lds16(Bp1 + kt, BsD1);
        __syncthreads();
        bf16x8 af[4], bfr[4];
        #pragma unroll
        for (int m = 0; m < 4; ++m) af[m] = *(const bf16x8*)&As[(wr + m * 16 + fr) * 32 + fk];
        #pragma unroll
        for (int n = 0; n < 4; ++n) bfr[n] = *(const bf16x8*)&Bs[(wc + n * 16 + fr) * 32 + fk];
        #pragma unroll
        for (int m = 0; m < 4; ++m)
            #pragma unroll
            for (int n = 0; n < 4; ++n)
                acc[m][n] = __builtin_amdgcn_mfma_f32_16x16x32_bf16(af[m], bfr[n], acc[m][n], 0, 0, 0);
        __syncthreads();
    }

    const int orow = (lane >> 4) * 4;
    #pragma unroll
    for (int m = 0; m < 4; ++m) {
        #pragma unroll
        for (int n = 0; n < 4; ++n) {
            const int d = bcol + wc + n * 16 + fr;
            #pragma unroll
            for (int j = 0; j < 4; ++j) {
                const int r = brow + wr + m * 16 + orow + j;
                if constexpr (EPI == 3) {
                    long xi = ((long)(z >> 3) * NN + r) * DD + (z & 7) * DKK + d;
                    float v = acc[m][n][j] + bfb2f(resb[xi]);
                    outp[xi] = f2bfb(v);
                }
            }
        }
    }
}

// ---------------- scores partials ----------------
__global__ __launch_bounds__(256, 2)
void k_scorespart(const unsigned short* __restrict__ Kb, const unsigned short* __restrict__ Vb,
                  float* __restrict__ part)
{
    __shared__ __align__(16) unsigned short KT[128 * 136];
    __shared__ __align__(16) unsigned short VT[128 * 136];
    const int tid = threadIdx.x;
    const int bh = blockIdx.y, split = blockIdx.x;
    const unsigned short* Kp = Kb + (long)bh * NN * DKK;
    const unsigned short* Vp = Vb + (long)bh * NN * DKK;
    const int lane = tid & 63, w = tid >> 6;
    const int wr = (w >> 1) * 64, wc = (w & 1) * 64, fr = lane & 15, fk = (lane >> 4) * 8;
    const int nrow = tid >> 1, dblk = (tid & 1) * 64;
    f32x4 acc[4][4] = {};
    for (int c = 0; c < 8; ++c) {
        const int n0 = (split * 8 + c) * 128;
        bf16x8 kv[8], vv[8];
        #pragma unroll
        for (int i = 0; i < 8; ++i) {
            kv[i] = *(const bf16x8*)&Kp[(long)(n0 + nrow) * DKK + dblk + i * 8];
            vv[i] = *(const bf16x8*)&Vp[(long)(n0 + nrow) * DKK + dblk + i * 8];
        }
        __syncthreads();
        #pragma unroll
        for (int i = 0; i < 8; ++i)
            #pragma unroll
            for (int j = 0; j < 8; ++j) {
                const int dd = dblk + i * 8 + j;
                KT[dd * 136 + nrow] = (unsigned short)kv[i][j];
                VT[dd * 136 + nrow] = (unsigned short)vv[i][j];
            }
        __syncthreads();
        #pragma unroll
        for (int ks = 0; ks < 4; ++ks) {
            bf16x8 af[4], bfr[4];
            #pragma unroll
            for (int m = 0; m < 4; ++m) af[m] = *(const bf16x8*)&KT[(wr + m * 16 + fr) * 136 + ks * 32 + fk];
            #pragma unroll
            for (int n = 0; n < 4; ++n) bfr[n] = *(const bf16x8*)&VT[(wc + n * 16 + fr) * 136 + ks * 32 + fk];
            #pragma unroll
            for (int m = 0; m < 4; ++m)
                #pragma unroll
                for (int n = 0; n < 4; ++n)
                    acc[m][n] = __builtin_amdgcn_mfma_f32_16x16x32_bf16(af[m], bfr[n], acc[m][n], 0, 0, 0);
        }
    }
    float* P = part + (long)(bh * 8 + split) * 16384;
    const int orow = (lane >> 4) * 4;
    #pragma unroll
    for (int m = 0; m < 4; ++m)
        #pragma unroll
        for (int n = 0; n < 4; ++n)
            #pragma unroll
            for (int j = 0; j < 4; ++j) {
                const int dD = wr + m * 16 + orow + j;
                const int e  = wc + n * 16 + fr;
                P[dD * 128 + e] = acc[m][n][j];
            }
}

__global__ void k_scoresred(const float* __restrict__ part, unsigned short* __restrict__ scT)
{
    const int bh = blockIdx.x, tid = threadIdx.x;
    const float* P = part + (long)bh * 8 * 16384;
    for (int i = tid; i < 16384; i += 256) {
        float s = 0.f;
        #pragma unroll
        for (int sp = 0; sp < 8; ++sp) s += P[sp * 16384 + i];
        const int d = i >> 7, e = i & 127;
        scT[(long)bh * 16384 + e * 128 + d] = f2bfb(s * (1.f / 8192.f));
    }
}

extern "C" void kernel_launch(void* const* d_in, const int* in_sizes, int n_in,
                              void* d_out, int out_size, void* d_ws, size_t ws_size,
                              hipStream_t stream)
{
    const float* x   = (const float*)d_in[0];
    const float* dx  = (const float*)d_in[1];
    const float* Wq  = (const float*)d_in[2];
    const float* bq  = (const float*)d_in[3];
    const float* Wk  = (const float*)d_in[4];
    const float* bk  = (const float*)d_in[5];
    const float* Wv  = (const float*)d_in[6];
    const float* bv  = (const float*)d_in[7];
    const float* gk  = (const float*)d_in[8];
    const float* bek = (const float*)d_in[9];
    const float* W1  = (const float*)d_in[10];
    const float* b1  = (const float*)d_in[11];
    const float* W2  = (const float*)d_in[12];
    const float* b2  = (const float*)d_in[13];
    float* out = (float*)d_out;
    (void)in_sizes; (void)n_in; (void)out_size; (void)ws_size;

    hipFuncSetAttribute((const void*)k_gemm256<1>, hipFuncAttributeMaxDynamicSharedMemorySize, 139264);
    hipFuncSetAttribute((const void*)k_gemm256<2>, hipFuncAttributeMaxDynamicSharedMemorySize, 131072);
    hipFuncSetAttribute((const void*)k_gemm256<3>, hipFuncAttributeMaxDynamicSharedMemorySize, 131072);

    char* ws = (char*)d_ws;
    size_t off = 0;
    auto alloc = [&](size_t bytes) { void* p = ws + off; off += (bytes + 255) & ~(size_t)255; return p; };
    unsigned short* WqkvT = (unsigned short*)alloc((size_t)3 * DD * DD * 2);  // [3072][1024]
    unsigned short* W1T   = (unsigned short*)alloc((size_t)FFF * DD * 2);
    unsigned short* W2T   = (unsigned short*)alloc((size_t)DD * FFF * 2);
    unsigned short* scT   = (unsigned short*)alloc((size_t)32 * 16384 * 2);
    unsigned short* xb    = (unsigned short*)alloc((size_t)MM * DD * 2);      // live through attn-x1; then hb
    unsigned short* Kb    = (unsigned short*)alloc((size_t)MM * DD * 2);
    unsigned short* Vb    = (unsigned short*)alloc((size_t)MM * DD * 2);
    unsigned short* x1b   = (unsigned short*)alloc((size_t)MM * DD * 2);
    unsigned short* hb    = xb;                        // h: 16384x4096 bf16 == xb+Kb region
    float* part           = (float*)x1b;               // dead before x1 written
    unsigned short* Qb    = (unsigned short*)out;      // d_out as Q scratch

    // 1. pack x -> bf16; transpose weights
    k_pack_bf16<<<dim3(((long)MM * DD) / 8 / 256), 256, 0, stream>>>(x, xb, (long)MM * DD);
    k_transpose_qkv<<<dim3(DD / 32, DD / 32, 3), 256, 0, stream>>>(Wq, Wk, Wv, WqkvT);
    k_transpose<<<dim3(FFF / 32, DD / 32), 256, 0, stream>>>(W1, W1T, DD, FFF);
    k_transpose<<<dim3(DD / 32, FFF / 32), 256, 0, stream>>>(W2, W2T, FFF, DD);

    // 2. fused QKV + per-head LN(K,V) + delta(K): tiles = 128x12 -> npass 6
    k_gemm256<1><<<dim3(256), 512, 139264, stream>>>(
        xb, DD, WqkvT, DD, bq, bk, bv, nullptr, Qb, Kb, Vb, nullptr,
        gk, bek, dx, DD, 3072 / 256, 6);

    // 3. scores = K^T V / N
    k_scorespart<<<dim3(8, 32), 256, 0, stream>>>(Kb, Vb, part);
    k_scoresred<<<dim3(32), 256, 0, stream>>>(part, scT);

    // 4. x1 = xb + Q @ scores (batched over b,h; residual from bf16 xb)
    k_gemm<3><<<dim3(1, NN / 128, BB * HH), 256, 0, stream>>>(Qb, DKK, (long)NN * DKK, scT, DKK, 16384L,
                                                              xb, x1b, DKK);

    // 5. FFN in 2 row-chunks of 16384
    for (int c = 0; c < 2; ++c) {
        const unsigned short* xc = x1b + (size_t)c * 16384 * DD;
        k_gemm256<2><<<dim3(256), 512, 131072, stream>>>(
            xc, DD, W1T, DD, b1, nullptr, nullptr, nullptr, hb, nullptr, nullptr, nullptr,
            nullptr, nullptr, nullptr, DD, FFF / 256, 4);
        k_gemm256<3><<<dim3(256), 512, 131072, stream>>>(
            hb, FFF, W2T, FFF, b2, nullptr, nullptr, xc, nullptr, nullptr, nullptr,
            out + (size_t)c * 16384 * DD, nullptr, nullptr, nullptr, FFF, DD / 256, 1);
    }
}

// Round 10
// 998.458 us; speedup vs baseline: 1.0742x; 1.0742x over previous
//
#include <hip/hip_runtime.h>
#include <hip/hip_bf16.h>
#include <stdint.h>

#define DEV __device__ __forceinline__

typedef __attribute__((ext_vector_type(8))) short bf16x8;
typedef __attribute__((ext_vector_type(8))) unsigned short u16x8;
typedef __attribute__((ext_vector_type(4))) unsigned short u16x4;
typedef __attribute__((ext_vector_type(4))) float f32x4;

static constexpr int BB = 4, NN = 8192, DD = 1024, HH = 8, DKK = 128, FFF = 4096;
static constexpr int MM = BB * NN;  // 32768

DEV float bfb2f(unsigned int s) { unsigned int x = s << 16; float f; __builtin_memcpy(&f, &x, 4); return f; }
DEV unsigned short f2bfb(float f) {
    unsigned int x; __builtin_memcpy(&x, &f, 4);
    x += 0x7fffu + ((x >> 16) & 1u);           // RNE
    return (unsigned short)(x >> 16);
}

DEV void gload_lds16(const void* g, void* l) {
    auto gp = (const __attribute__((address_space(1))) void*)(uintptr_t)g;
    auto lp = (__attribute__((address_space(3))) void*)(unsigned int)(uintptr_t)l;
    __builtin_amdgcn_global_load_lds(gp, lp, 16, 0, 0);
}

// ---------------- fp32 -> bf16 pack ----------------
__global__ void k_pack_bf16(const float* __restrict__ in, unsigned short* __restrict__ ob, long n) {
    long i = ((long)blockIdx.x * blockDim.x + threadIdx.x) * 8;
    if (i >= n) return;
    f32x4 a = *(const f32x4*)&in[i];
    f32x4 b = *(const f32x4*)&in[i + 4];
    u16x8 o;
    o[0]=f2bfb(a[0]); o[1]=f2bfb(a[1]); o[2]=f2bfb(a[2]); o[3]=f2bfb(a[3]);
    o[4]=f2bfb(b[0]); o[5]=f2bfb(b[1]); o[6]=f2bfb(b[2]); o[7]=f2bfb(b[3]);
    *(u16x8*)&ob[i] = o;
}

// ---------------- W [R,C] fp32 -> W^T [C,R] bf16 ----------------
DEV void transpose_body(const float* __restrict__ W, unsigned short* __restrict__ WT, int R, int C,
                        int bx, int by, int tid) {
    __shared__ float t[32][33];
    const int r0 = by * 32, c0 = bx * 32;
    const int lr = tid >> 3, lc = (tid & 7) * 4;
    f32x4 v = *(const f32x4*)&W[(long)(r0 + lr) * C + c0 + lc];
    t[lr][lc + 0] = v[0]; t[lr][lc + 1] = v[1]; t[lr][lc + 2] = v[2]; t[lr][lc + 3] = v[3];
    __syncthreads();
    const int oc = tid >> 3, orr = (tid & 7) * 4;
    u16x4 o;
    o[0] = f2bfb(t[orr + 0][oc]); o[1] = f2bfb(t[orr + 1][oc]);
    o[2] = f2bfb(t[orr + 2][oc]); o[3] = f2bfb(t[orr + 3][oc]);
    *(u16x4*)&WT[(long)(c0 + oc) * R + r0 + orr] = o;
}
__global__ void k_transpose(const float* __restrict__ W, unsigned short* __restrict__ WT, int R, int C) {
    transpose_body(W, WT, R, C, blockIdx.x, blockIdx.y, threadIdx.x);
}
__global__ void k_transpose_qkv(const float* __restrict__ Wq, const float* __restrict__ Wk,
                                const float* __restrict__ Wv, unsigned short* __restrict__ WT) {
    const float* W = blockIdx.z == 0 ? Wq : (blockIdx.z == 1 ? Wk : Wv);
    transpose_body(W, WT + (size_t)blockIdx.z * DD * DD, DD, DD, blockIdx.x, blockIdx.y, threadIdx.x);
}

// ============ 256x256 8-phase GEMM, persistent blocks + periodic ring (R8-exact) ============
template <int EPI>
__global__ __launch_bounds__(512, 2)
void k_gemm256(const unsigned short* __restrict__ A, int lda,
               const unsigned short* __restrict__ BT, int ldbt,
               const float* __restrict__ bias0, const float* __restrict__ bias1,
               const float* __restrict__ bias2,
               const unsigned short* __restrict__ resb,
               unsigned short* __restrict__ outp0, unsigned short* __restrict__ outp1,
               unsigned short* __restrict__ outp2,
               float* __restrict__ outf,
               int K, int gridx, int npass)
{
    extern __shared__ __align__(128) unsigned short smem[];
    unsigned short* As = smem;              // 4 slots * 8192 shorts
    unsigned short* Bs = smem + 4 * 8192;

    const int wg0 = (blockIdx.x & 7) * 32 + (blockIdx.x >> 3);   // XCD-chunked bijection

    const int tid = threadIdx.x;
    const int lane = tid & 63;
    const int w = tid >> 6;
    const int wm = w >> 2, wn = w & 3;      // 8 waves: 2M x 4N
    const int fr = lane & 15;
    const int kg = lane >> 4;

    const int dl = tid * 16;
    const int soff = dl ^ (((dl >> 7) & 3) << 4);
    const int arow = soff >> 6;
    const int akel = (soff & 63) >> 1;

    int aoff[8], boff[4];
    #pragma unroll
    for (int m = 0; m < 8; ++m) { int o = (wm * 128 + m * 16 + fr) * 64 + kg * 16; aoff[m] = o ^ (((o >> 7) & 3) << 4); }
    #pragma unroll
    for (int n = 0; n < 4; ++n) { int o = (wn * 64 + n * 16 + fr) * 64 + kg * 16; boff[n] = o ^ (((o >> 7) & 3) << 4); }

#define STG_A(base, u, ks, slot) do { \
        const unsigned short* _g = (base) + (long)(u) * 64 + (ks) * 32; \
        gload_lds16(_g,              (slot) + tid * 8); \
        gload_lds16(_g + 128L * lda, (slot) + 4096 + tid * 8); } while (0)
#define STG_B(base, u, ks, slot) do { \
        const unsigned short* _g = (base) + (long)(u) * 64 + (ks) * 32; \
        gload_lds16(_g,               (slot) + tid * 8); \
        gload_lds16(_g + 128L * ldbt, (slot) + 4096 + tid * 8); } while (0)

#define BAR() __builtin_amdgcn_s_barrier()
#define LGKM(N) do { asm volatile("s_waitcnt lgkmcnt(" #N ")" ::: "memory"); \
                     __builtin_amdgcn_sched_barrier(0); } while (0)
#define VM8() asm volatile("s_waitcnt vmcnt(8)" ::: "memory")

#define MFMA16(AF, BF, R0) do { \
        __builtin_amdgcn_s_setprio(1); \
        _Pragma("unroll") \
        for (int m = 0; m < 4; ++m) { \
            _Pragma("unroll") \
            for (int n = 0; n < 4; ++n) \
                acc[(R0) + m][n] = __builtin_amdgcn_mfma_f32_16x16x32_bf16(AF[m], BF[n], acc[(R0) + m][n], 0, 0, 0); \
        } \
        __builtin_amdgcn_s_setprio(0); } while (0)

    // R8-exact: ph0/ph2 issue 12 reads + lgkmcnt(4); ph1/ph3 none + lgkmcnt(0)
#define DO_TILE(sa0, sa1, sb0, sb1, STG0, STG1, STG2, STG3) do { \
        bf16x8 b0f[4], a0f[4], a1f[4], b1f[4], a2f[4], a3f[4]; \
        _Pragma("unroll") \
        for (int n = 0; n < 4; ++n) b0f[n] = *(const bf16x8*)((const char*)(sb0) + boff[n]); \
        _Pragma("unroll") \
        for (int m = 0; m < 4; ++m) a0f[m] = *(const bf16x8*)((const char*)(sa0) + aoff[m]); \
        _Pragma("unroll") \
        for (int m = 0; m < 4; ++m) a1f[m] = *(const bf16x8*)((const char*)(sa0) + aoff[m + 4]); \
        STG0; \
        BAR(); LGKM(4); \
        MFMA16(a0f, b0f, 0); \
        BAR(); \
        STG1; VM8(); \
        BAR(); LGKM(0); \
        MFMA16(a1f, b0f, 4); \
        BAR(); \
        _Pragma("unroll") \
        for (int n = 0; n < 4; ++n) b1f[n] = *(const bf16x8*)((const char*)(sb1) + boff[n]); \
        _Pragma("unroll") \
        for (int m = 0; m < 4; ++m) a2f[m] = *(const bf16x8*)((const char*)(sa1) + aoff[m]); \
        _Pragma("unroll") \
        for (int m = 0; m < 4; ++m) a3f[m] = *(const bf16x8*)((const char*)(sa1) + aoff[m + 4]); \
        STG2; \
        BAR(); LGKM(4); \
        MFMA16(a2f, b1f, 0); \
        BAR(); \
        STG3; VM8(); \
        BAR(); LGKM(0); \
        MFMA16(a3f, b1f, 4); \
        BAR(); \
    } while (0)

    unsigned short* A0 = As;            unsigned short* A1 = As + 8192;
    unsigned short* A2 = As + 16384;    unsigned short* A3 = As + 24576;
    unsigned short* B0 = Bs;            unsigned short* B1 = Bs + 8192;
    unsigned short* B2 = Bs + 16384;    unsigned short* B3 = Bs + 24576;

    const int NT = K >> 6;

    int brow = (wg0 / gridx) * 256;
    int bcol = (wg0 % gridx) * 256;
    const unsigned short* Ab = A + (long)(brow + arow) * lda + akel;
    const unsigned short* Bb = BT + (long)(bcol + arow) * ldbt + akel;
    STG_A(Ab, 0, 0, A0); STG_B(Bb, 0, 0, B0);
    STG_B(Bb, 0, 1, B1); STG_A(Ab, 0, 1, A1);
    STG_A(Ab, 1, 0, A2); STG_B(Bb, 1, 0, B2);
    VM8();
    BAR();

    for (int p = 0; p < npass; ++p) {
        const int wgN = (p + 1 < npass) ? (wg0 + (p + 1) * 256) : wg0;
        const int browN = (wgN / gridx) * 256;
        const int bcolN = (wgN % gridx) * 256;
        const unsigned short* Ab2 = A + (long)(browN + arow) * lda + akel;
        const unsigned short* Bb2 = BT + (long)(bcolN + arow) * ldbt + akel;

        f32x4 acc[8][4] = {};

        for (int t = 0; t + 2 < NT; t += 2) {
            DO_TILE(A0, A1, B0, B1,
                    STG_B(Bb, t + 1, 1, B3), STG_A(Ab, t + 1, 1, A3),
                    STG_A(Ab, t + 2, 0, A0), STG_B(Bb, t + 2, 0, B0));
            DO_TILE(A2, A3, B2, B3,
                    STG_B(Bb, t + 2, 1, B1), STG_A(Ab, t + 2, 1, A1),
                    STG_A(Ab, t + 3, 0, A2), STG_B(Bb, t + 3, 0, B2));
        }
        DO_TILE(A0, A1, B0, B1,
                STG_B(Bb, NT - 1, 1, B3), STG_A(Ab, NT - 1, 1, A3),
                STG_A(Ab2, 0, 0, A0), STG_B(Bb2, 0, 0, B0));
        DO_TILE(A2, A3, B2, B3,
                STG_B(Bb2, 0, 1, B1), STG_A(Ab2, 0, 1, A1),
                STG_A(Ab2, 1, 0, A2), STG_B(Bb2, 1, 0, B2));

        const int q4 = (lane >> 4) * 4;
        if constexpr (EPI == 1) {
            const int mat = bcol >> 10;
            const float* bp = mat == 0 ? bias0 : (mat == 1 ? bias1 : bias2);
            unsigned short* op = mat == 0 ? outp0 : (mat == 1 ? outp1 : outp2);
            const int dc0 = bcol & 1023;
            #pragma unroll
            for (int m = 0; m < 8; ++m)
                #pragma unroll
                for (int n = 0; n < 4; ++n) {
                    const int c = dc0 + wn * 64 + n * 16 + fr;
                    const float bv = bp[c];
                    const int hh = c >> 7, dk = c & 127;
                    #pragma unroll
                    for (int j = 0; j < 4; ++j) {
                        const int r = brow + wm * 128 + m * 16 + q4 + j;
                        const long idx = (((long)(r >> 13) * 8 + hh) * 8192 + (r & 8191)) * 128 + dk;
                        op[idx] = f2bfb(acc[m][n][j] + bv);
                    }
                }
        } else if constexpr (EPI == 2) {
            #pragma unroll
            for (int m = 0; m < 8; ++m)
                #pragma unroll
                for (int n = 0; n < 4; ++n) {
                    const int c = bcol + wn * 64 + n * 16 + fr;
                    const float bv = bias0[c];
                    #pragma unroll
                    for (int j = 0; j < 4; ++j) {
                        const int r = brow + wm * 128 + m * 16 + q4 + j;
                        float v = acc[m][n][j] + bv;
                        v = v / (1.f + __expf(-v));
                        outp0[(long)r * FFF + c] = f2bfb(v);
                    }
                }
        } else {
            #pragma unroll
            for (int m = 0; m < 8; ++m)
                #pragma unroll
                for (int n = 0; n < 4; ++n) {
                    const int c = bcol + wn * 64 + n * 16 + fr;
                    const float bv = bias0[c];
                    #pragma unroll
                    for (int j = 0; j < 4; ++j) {
                        const int r = brow + wm * 128 + m * 16 + q4 + j;
                        float v = acc[m][n][j] + bv + bfb2f(resb[(long)r * DD + c]);
                        outf[(long)r * DD + c] = v;
                    }
                }
        }

        brow = browN; bcol = bcolN; Ab = Ab2; Bb = Bb2;
    }
    asm volatile("s_waitcnt vmcnt(0)" ::: "memory");
#undef DO_TILE
#undef MFMA16
#undef VM8
#undef LGKM
#undef BAR
#undef STG_A
#undef STG_B
}

// ---------------- 128x128 GEMM (attn: EPI 3, residual from bf16 xb) ----------------
template <int EPI>
__global__ __launch_bounds__(256, 2)
void k_gemm(const unsigned short* __restrict__ A, int lda, long sAz,
            const unsigned short* __restrict__ BT, int ldbt, long sBz,
            const unsigned short* __restrict__ resb,
            unsigned short* __restrict__ outp,
            int K)
{
    __shared__ __align__(16) unsigned short As[128 * 32];
    __shared__ __align__(16) unsigned short Bs[128 * 32];
    const int tid = threadIdx.x;
    const int z = blockIdx.z;
    A  += (long)z * sAz;
    BT += (long)z * sBz;
    const int brow = blockIdx.y * 128;
    const int bcol = blockIdx.x * 128;

    const int c0 = tid, c1 = tid + 256;
    const unsigned short* Ap0 = A + (long)(brow + (c0 >> 2)) * lda + (c0 & 3) * 8;
    const unsigned short* Ap1 = A + (long)(brow + (c1 >> 2)) * lda + (c1 & 3) * 8;
    const unsigned short* Bp0 = BT + (long)(bcol + (c0 >> 2)) * ldbt + (c0 & 3) * 8;
    const unsigned short* Bp1 = BT + (long)(bcol + (c1 >> 2)) * ldbt + (c1 & 3) * 8;
    unsigned short* AsD0 = &As[c0 * 8];
    unsigned short* AsD1 = &As[c1 * 8];
    unsigned short* BsD0 = &Bs[c0 * 8];
    unsigned short* BsD1 = &Bs[c1 * 8];

    const int lane = tid & 63;
    const int w = tid >> 6;
    const int wr = (w >> 1) * 64;
    const int wc = (w & 1) * 64;
    const int fr = lane & 15;
    const int fk = (lane >> 4) * 8;

    f32x4 acc[4][4] = {};

    for (int kt = 0; kt < K; kt += 32) {
        gload_lds16(Ap0 + kt, AsD0);
        gload_lds16(Ap1 + kt, AsD1);
        gload_lds16(Bp0 + kt, BsD0);
        gload_lds16(Bp1 + kt, BsD1);
        __syncthreads();
        bf16x8 af[4], bfr[4];
        #pragma unroll
        for (int m = 0; m < 4; ++m) af[m] = *(const bf16x8*)&As[(wr + m * 16 + fr) * 32 + fk];
        #pragma unroll
        for (int n = 0; n < 4; ++n) bfr[n] = *(const bf16x8*)&Bs[(wc + n * 16 + fr) * 32 + fk];
        #pragma unroll
        for (int m = 0; m < 4; ++m)
            #pragma unroll
            for (int n = 0; n < 4; ++n)
                acc[m][n] = __builtin_amdgcn_mfma_f32_16x16x32_bf16(af[m], bfr[n], acc[m][n], 0, 0, 0);
        __syncthreads();
    }

    const int orow = (lane >> 4) * 4;
    #pragma unroll
    for (int m = 0; m < 4; ++m) {
        #pragma unroll
        for (int n = 0; n < 4; ++n) {
            const int d = bcol + wc + n * 16 + fr;
            #pragma unroll
            for (int j = 0; j < 4; ++j) {
                const int r = brow + wr + m * 16 + orow + j;
                if constexpr (EPI == 3) {
                    long xi = ((long)(z >> 3) * NN + r) * DD + (z & 7) * DKK + d;
                    float v = acc[m][n][j] + bfb2f(resb[xi]);
                    outp[xi] = f2bfb(v);
                }
            }
        }
    }
}

// ---------------- in-place per-head LN on K and V (+delta on K) ----------------
__global__ void k_ln(unsigned short* __restrict__ Kb, unsigned short* __restrict__ Vb,
                     const float* __restrict__ gk, const float* __restrict__ bek,
                     const float* __restrict__ dx)
{
    const int tid = threadIdx.x;
    const int lane = tid & 63;
    const long row = (long)blockIdx.x * 4 + (tid >> 6);
    unsigned short* buf = blockIdx.y ? Vb : Kb;
    const int h = (int)((row >> 13) & 7);
    const int n = (int)(row & 8191);
    unsigned int* p = (unsigned int*)(buf + row * 128) + lane;
    const unsigned int u = *p;
    float f0 = bfb2f(u & 0xffffu);
    float f1 = bfb2f(u >> 16);
    float s = f0 + f1, q = f0 * f0 + f1 * f1;
    #pragma unroll
    for (int o = 32; o; o >>= 1) { s += __shfl_xor(s, o); q += __shfl_xor(q, o); }
    const float mean = s * (1.f / 128.f);
    const float var  = q * (1.f / 128.f) - mean * mean;
    const float rstd = rsqrtf(var + 1e-5f);
    const int gi = h * 128 + lane * 2;
    float o0 = (f0 - mean) * rstd * gk[gi]     + bek[gi];
    float o1 = (f1 - mean) * rstd * gk[gi + 1] + bek[gi + 1];
    if (blockIdx.y == 0) { const float dl = dx[n]; o0 *= dl; o1 *= dl; }
    *p = (unsigned int)f2bfb(o0) | ((unsigned int)f2bfb(o1) << 16);
}

// ---------------- scores partials ----------------
__global__ __launch_bounds__(256, 2)
void k_scorespart(const unsigned short* __restrict__ Kb, const unsigned short* __restrict__ Vb,
                  float* __restrict__ part)
{
    __shared__ __align__(16) unsigned short KT[128 * 136];
    __shared__ __align__(16) unsigned short VT[128 * 136];
    const int tid = threadIdx.x;
    const int bh = blockIdx.y, split = blockIdx.x;
    const unsigned short* Kp = Kb + (long)bh * NN * DKK;
    const unsigned short* Vp = Vb + (long)bh * NN * DKK;
    const int lane = tid & 63, w = tid >> 6;
    const int wr = (w >> 1) * 64, wc = (w & 1) * 64, fr = lane & 15, fk = (lane >> 4) * 8;
    const int nrow = tid >> 1, dblk = (tid & 1) * 64;
    f32x4 acc[4][4] = {};
    for (int c = 0; c < 8; ++c) {
        const int n0 = (split * 8 + c) * 128;
        bf16x8 kv[8], vv[8];
        #pragma unroll
        for (int i = 0; i < 8; ++i) {
            kv[i] = *(const bf16x8*)&Kp[(long)(n0 + nrow) * DKK + dblk + i * 8];
            vv[i] = *(const bf16x8*)&Vp[(long)(n0 + nrow) * DKK + dblk + i * 8];
        }
        __syncthreads();
        #pragma unroll
        for (int i = 0; i < 8; ++i)
            #pragma unroll
            for (int j = 0; j < 8; ++j) {
                const int dd = dblk + i * 8 + j;
                KT[dd * 136 + nrow] = (unsigned short)kv[i][j];
                VT[dd * 136 + nrow] = (unsigned short)vv[i][j];
            }
        __syncthreads();
        #pragma unroll
        for (int ks = 0; ks < 4; ++ks) {
            bf16x8 af[4], bfr[4];
            #pragma unroll
            for (int m = 0; m < 4; ++m) af[m] = *(const bf16x8*)&KT[(wr + m * 16 + fr) * 136 + ks * 32 + fk];
            #pragma unroll
            for (int n = 0; n < 4; ++n) bfr[n] = *(const bf16x8*)&VT[(wc + n * 16 + fr) * 136 + ks * 32 + fk];
            #pragma unroll
            for (int m = 0; m < 4; ++m)
                #pragma unroll
                for (int n = 0; n < 4; ++n)
                    acc[m][n] = __builtin_amdgcn_mfma_f32_16x16x32_bf16(af[m], bfr[n], acc[m][n], 0, 0, 0);
        }
    }
    float* P = part + (long)(bh * 8 + split) * 16384;
    const int orow = (lane >> 4) * 4;
    #pragma unroll
    for (int m = 0; m < 4; ++m)
        #pragma unroll
        for (int n = 0; n < 4; ++n)
            #pragma unroll
            for (int j = 0; j < 4; ++j) {
                const int dD = wr + m * 16 + orow + j;
                const int e  = wc + n * 16 + fr;
                P[dD * 128 + e] = acc[m][n][j];
            }
}

__global__ void k_scoresred(const float* __restrict__ part, unsigned short* __restrict__ scT)
{
    const int bh = blockIdx.x, tid = threadIdx.x;
    const float* P = part + (long)bh * 8 * 16384;
    for (int i = tid; i < 16384; i += 256) {
        float s = 0.f;
        #pragma unroll
        for (int sp = 0; sp < 8; ++sp) s += P[sp * 16384 + i];
        const int d = i >> 7, e = i & 127;
        scT[(long)bh * 16384 + e * 128 + d] = f2bfb(s * (1.f / 8192.f));
    }
}

extern "C" void kernel_launch(void* const* d_in, const int* in_sizes, int n_in,
                              void* d_out, int out_size, void* d_ws, size_t ws_size,
                              hipStream_t stream)
{
    const float* x   = (const float*)d_in[0];
    const float* dx  = (const float*)d_in[1];
    const float* Wq  = (const float*)d_in[2];
    const float* bq  = (const float*)d_in[3];
    const float* Wk  = (const float*)d_in[4];
    const float* bk  = (const float*)d_in[5];
    const float* Wv  = (const float*)d_in[6];
    const float* bv  = (const float*)d_in[7];
    const float* gk  = (const float*)d_in[8];
    const float* bek = (const float*)d_in[9];
    const float* W1  = (const float*)d_in[10];
    const float* b1  = (const float*)d_in[11];
    const float* W2  = (const float*)d_in[12];
    const float* b2  = (const float*)d_in[13];
    float* out = (float*)d_out;
    (void)in_sizes; (void)n_in; (void)out_size; (void)ws_size;

    hipFuncSetAttribute((const void*)k_gemm256<1>, hipFuncAttributeMaxDynamicSharedMemorySize, 131072);
    hipFuncSetAttribute((const void*)k_gemm256<2>, hipFuncAttributeMaxDynamicSharedMemorySize, 131072);
    hipFuncSetAttribute((const void*)k_gemm256<3>, hipFuncAttributeMaxDynamicSharedMemorySize, 131072);

    char* ws = (char*)d_ws;
    size_t off = 0;
    auto alloc = [&](size_t bytes) { void* p = ws + off; off += (bytes + 255) & ~(size_t)255; return p; };
    unsigned short* WqkvT = (unsigned short*)alloc((size_t)3 * DD * DD * 2);  // [3072][1024]
    unsigned short* W1T   = (unsigned short*)alloc((size_t)FFF * DD * 2);
    unsigned short* W2T   = (unsigned short*)alloc((size_t)DD * FFF * 2);
    unsigned short* scT   = (unsigned short*)alloc((size_t)32 * 16384 * 2);
    unsigned short* xb    = (unsigned short*)alloc((size_t)MM * DD * 2);      // live through attn-x1; then hb
    unsigned short* Kb    = (unsigned short*)alloc((size_t)MM * DD * 2);
    unsigned short* Vb    = (unsigned short*)alloc((size_t)MM * DD * 2);
    unsigned short* x1b   = (unsigned short*)alloc((size_t)MM * DD * 2);
    unsigned short* hb    = xb;                        // h: 16384x4096 bf16 == xb+Kb region
    float* part           = (float*)x1b;               // dead before x1 written
    unsigned short* Qb    = (unsigned short*)out;      // d_out as Q scratch

    // 1. pack x -> bf16; transpose weights
    k_pack_bf16<<<dim3(((long)MM * DD) / 8 / 256), 256, 0, stream>>>(x, xb, (long)MM * DD);
    k_transpose_qkv<<<dim3(DD / 32, DD / 32, 3), 256, 0, stream>>>(Wq, Wk, Wv, WqkvT);
    k_transpose<<<dim3(FFF / 32, DD / 32), 256, 0, stream>>>(W1, W1T, DD, FFF);
    k_transpose<<<dim3(DD / 32, FFF / 32), 256, 0, stream>>>(W2, W2T, FFF, DD);

    // 2. fused QKV: tiles = 128x12 = 1536 -> npass 6
    k_gemm256<1><<<dim3(256), 512, 131072, stream>>>(
        xb, DD, WqkvT, DD, bq, bk, bv, nullptr, Qb, Kb, Vb, nullptr, DD, 3072 / 256, 6);

    // 3. per-head LN on K and V, delta on K
    k_ln<<<dim3((BB * HH * NN) / 4, 2), 256, 0, stream>>>(Kb, Vb, gk, bek, dx);

    // 4. scores = K^T V / N
    k_scorespart<<<dim3(8, 32), 256, 0, stream>>>(Kb, Vb, part);
    k_scoresred<<<dim3(32), 256, 0, stream>>>(part, scT);

    // 5. x1 = xb + Q @ scores (batched over b,h; residual from bf16 xb)
    k_gemm<3><<<dim3(1, NN / 128, BB * HH), 256, 0, stream>>>(Qb, DKK, (long)NN * DKK, scT, DKK, 16384L,
                                                              xb, x1b, DKK);

    // 6. FFN in 2 row-chunks of 16384
    for (int c = 0; c < 2; ++c) {
        const unsigned short* xc = x1b + (size_t)c * 16384 * DD;
        k_gemm256<2><<<dim3(256), 512, 131072, stream>>>(
            xc, DD, W1T, DD, b1, nullptr, nullptr, nullptr, hb, nullptr, nullptr, nullptr, DD, FFF / 256, 4);
        k_gemm256<3><<<dim3(256), 512, 131072, stream>>>(
            hb, FFF, W2T, FFF, b2, nullptr, nullptr, xc, nullptr, nullptr, nullptr,
            out + (size_t)c * 16384 * DD, FFF, DD / 256, 1);
    }
}